// Round 19
// baseline (955.946 us; speedup 1.0000x reference)
//
#include <hip/hip_runtime.h>
#include <hip/hip_bf16.h>
#include <cstdint>

// ---------------------------------------------------------------------------
// KAN 2-layer forward as two bf16 MFMA GEMMs (fp32 output).
// Round-19 = r18 (best, 790us) + L1 occupancy fix:
//  * L1 GEMM tile BN=128 -> BN=64 (BM=128): grid (16,32)=512 blocks =
//    2 blocks/CU (was 256 = 1/CU — the same grid-limited deficit r15's fix
//    removed for L0 at +24%). acc[4][1]=16 regs, LDS 3x12KB=36KB, ~70 live
//    VGPR -> no spill at (512,4). B-staging: 256-thread map duplicated
//    across wave-halves (identical bytes, benign race; every wave issues
//    exactly 2 GLD16/tile so counted vmcnt stays uniform: L=2).
//  * L0 path, prep_merge aux, ws layout: r18-FROZEN.
// ws = r3-proven 255,852,544 B: h1 | W | Aug region. CH=4096.
// ---------------------------------------------------------------------------

typedef __attribute__((ext_vector_type(8))) short short8;
typedef __attribute__((ext_vector_type(4))) short short4v;
typedef __attribute__((ext_vector_type(4))) float f32x4;

#define GLD16(gp, lp)                                                          \
  __builtin_amdgcn_global_load_lds(                                           \
      (const __attribute__((address_space(1))) unsigned int*)(gp),             \
      (__attribute__((address_space(3))) unsigned int*)(lp), 16, 0, 0)

__device__ __forceinline__ unsigned short f2bf(float f) {
  __hip_bfloat16 h = __float2bfloat16(f);
  return *reinterpret_cast<unsigned short*>(&h);
}

__device__ __forceinline__ void basis8(float x, float* w, int& j) {
  float u  = (x + 2.2f) * 2.5f;
  float fj = floorf(u);
  j = (int)fj;
  float t  = u - fj;
  float omt = 1.0f - t;
  float t2 = t * t, t3 = t2 * t;
  w[0] = omt * omt * omt * (1.0f / 6.0f);                              // d==3
  w[1] = (3.0f * t3 - 6.0f * t2 + 4.0f) * (1.0f / 6.0f);               // d==2
  w[2] = (-3.0f * t3 + 3.0f * t2 + 3.0f * t + 1.0f) * (1.0f / 6.0f);   // d==1
  w[3] = t3 * (1.0f / 6.0f);                                           // d==0
}

// ---- prep_w item: W[o, kperm(c,i)], kperm = (i/64)*576 + c*64 + (i%64) ----
__device__ __forceinline__ void prep_w_item(
    long idx, const float* __restrict__ coef, const float* __restrict__ sb,
    const float* __restrict__ sp, const float* __restrict__ mask,
    __hip_bfloat16* __restrict__ W, int I) {
  int qtr = I >> 2;
  int iq = (int)(idx % qtr);
  int o  = (int)(idx / qtr);
  int i  = iq << 2;
  size_t oi = (size_t)o * I + i;
  float4 mk4 = *(const float4*)(mask + oi);
  float4 sp4 = *(const float4*)(sp + oi);
  float4 sb4 = *(const float4*)(sb + oi);
  float spm[4] = {sp4.x * mk4.x, sp4.y * mk4.y, sp4.z * mk4.z, sp4.w * mk4.w};
  float cf[4][8];
  const float4* cp = (const float4*)(coef + oi * 8);
#pragma unroll
  for (int e = 0; e < 4; e++) {
    float4 a = cp[e * 2], b = cp[e * 2 + 1];
    cf[e][0] = a.x; cf[e][1] = a.y; cf[e][2] = a.z; cf[e][3] = a.w;
    cf[e][4] = b.x; cf[e][5] = b.y; cf[e][6] = b.z; cf[e][7] = b.w;
  }
  __hip_bfloat16* base = W + (size_t)o * (size_t)(9 * I) + (i >> 6) * 576 + (i & 63);
#pragma unroll
  for (int c = 0; c < 8; c++) {
    short4v pk;
#pragma unroll
    for (int e = 0; e < 4; e++) pk[e] = (short)f2bf(cf[e][c] * spm[e]);
    *(short4v*)(base + c * 64) = pk;
  }
  short4v ps;
  ps[0] = (short)f2bf(sb4.x * mk4.x); ps[1] = (short)f2bf(sb4.y * mk4.y);
  ps[2] = (short)f2bf(sb4.z * mk4.z); ps[3] = (short)f2bf(sb4.w * mk4.w);
  *(short4v*)(base + 8 * 64) = ps;
}

// ---- expand item: Aug[b, kperm(c,i)], 8 elems ------------------------------
__device__ __forceinline__ void expand_item(
    long idx, const float* __restrict__ src, __hip_bfloat16* __restrict__ aug,
    int I) {
  int  oct = I >> 3;
  int  io = (int)(idx % oct);
  long b  = idx / oct;
  int  i  = io << 3;
  const float* sp = src + b * (size_t)I + i;
  float4 xa = *(const float4*)sp;
  float4 xb = *(const float4*)(sp + 4);
  float xv[8] = {xa.x, xa.y, xa.z, xa.w, xb.x, xb.y, xb.z, xb.w};

  float w[8][4], s[8];
  int   j[8];
#pragma unroll
  for (int e = 0; e < 8; e++) {
    float xe = xv[e];
    s[e] = xe / (1.0f + __expf(-xe));
    basis8(xe, w[e], j[e]);
  }
  __hip_bfloat16* base = aug + b * (size_t)(9 * I) + (i >> 6) * 576 + (i & 63);
#pragma unroll
  for (int c = 0; c < 8; c++) {
    short8 pk;
#pragma unroll
    for (int e = 0; e < 8; e++) {
      int d = j[e] - c;
      float v = 0.0f;
      v = (d == 0) ? w[e][3] : v;
      v = (d == 1) ? w[e][2] : v;
      v = (d == 2) ? w[e][1] : v;
      v = (d == 3) ? w[e][0] : v;
      pk[e] = (short)f2bf(v);
    }
    *(short8*)(base + c * 64) = pk;
  }
  short8 ps;
#pragma unroll
  for (int e = 0; e < 8; e++) ps[e] = (short)f2bf(s[e]);
  *(short8*)(base + 8 * 64) = ps;
}

// ---- merged prep: {W-pack items} then {expand octets} ----------------------
__global__ void prep_merge(
    const float* __restrict__ coef, const float* __restrict__ sb,
    const float* __restrict__ sp, const float* __restrict__ mask,
    __hip_bfloat16* __restrict__ W, int IW, long nW,
    const float* __restrict__ xsrc, __hip_bfloat16* __restrict__ aug,
    int IX, long nX) {
  long idx = (long)blockIdx.x * blockDim.x + threadIdx.x;
  if (idx < nW)            prep_w_item(idx, coef, sb, sp, mask, W, IW);
  else if (idx < nW + nX)  expand_item(idx - nW, xsrc, aug, IX);
}

__global__ void expand_aug(const float* __restrict__ src,
                           __hip_bfloat16* __restrict__ aug,
                           long totalOcts, int I) {
  long idx = (long)blockIdx.x * blockDim.x + threadIdx.x;
  if (idx >= totalOcts) return;
  expand_item(idx, src, aug, I);
}

// ---- L0 GEMM (r15-verbatim): BM=128 x BN=256 -------------------------------
template <int BN>
__global__ __launch_bounds__(512, 4) void gemm128(
    const __hip_bfloat16* __restrict__ A, const __hip_bfloat16* __restrict__ Bw,
    const float* __restrict__ bias, float* __restrict__ Cout, int N, int K) {
  constexpr int WN   = BN / 4;
  constexpr int NREP = BN / 64;
  constexpr int BUFB = 8192 + BN * 64;
  __shared__ __attribute__((aligned(16))) char lds[3 * BUFB];

  const int t = threadIdx.x;
  const int w = t >> 6, l = t & 63;
  const int wr = w >> 2, wc = w & 3;
  const int lr = l & 15;
  const int kbs = ((l >> 4) * 16) ^ (((lr >> 1) & 3) << 4);

  unsigned nwg = gridDim.x * gridDim.y;
  unsigned lin = blockIdx.y * gridDim.x + blockIdx.x;
  unsigned swz = (lin & 7) * (nwg >> 3) + (lin >> 3);
  unsigned bx = swz % gridDim.x, by = swz / gridDim.x;
  size_t brow = (size_t)by * 128, bcol = (size_t)bx * BN;

  f32x4 acc[4][NREP];
#pragma unroll
  for (int m = 0; m < 4; m++)
#pragma unroll
    for (int n = 0; n < NREP; n++) acc[m][n] = (f32x4){0.f, 0.f, 0.f, 0.f};

  const int srow  = t >> 2;
  const int scolb = ((t & 3) * 16) ^ (((srow >> 1) & 3) << 4);
  const __hip_bfloat16* gA0 = A + (brow + srow) * (size_t)K + (scolb >> 1);
  const __hip_bfloat16* gB0 = Bw + (bcol + srow) * (size_t)K + (scolb >> 1);
  const __hip_bfloat16* gB1 = gB0 + (size_t)128 * K;

  char* ldsp = (char*)lds;
  const int paOff = (wr * 64 + lr) * 64 + kbs;
  const int pbOff = 8192 + (wc * WN + lr) * 64 + kbs;

  auto STAGE = [&](int kt, int q) {
    char* bp = ldsp + q * BUFB;
    GLD16(gA0 + (kt << 5), bp + w * 1024);
    GLD16(gB0 + (kt << 5), bp + 8192 + w * 1024);
    if constexpr (BN == 256) GLD16(gB1 + (kt << 5), bp + 16384 + w * 1024);
  };
  auto COMPUTE = [&](int q) {
    const char* pa = ldsp + q * BUFB + paOff;
    const char* pb = ldsp + q * BUFB + pbOff;
    short8 bq[NREP], aq[4];
#pragma unroll
    for (int n = 0; n < NREP; n++) bq[n] = *(const short8*)(pb + n * 1024);
#pragma unroll
    for (int m = 0; m < 4; m++) aq[m] = *(const short8*)(pa + m * 1024);
    __builtin_amdgcn_s_setprio(1);
#pragma unroll
    for (int m = 0; m < 4; m++)
#pragma unroll
      for (int n = 0; n < NREP; n++)
        acc[m][n] = __builtin_amdgcn_mfma_f32_16x16x32_bf16(aq[m], bq[n], acc[m][n], 0, 0, 0);
    __builtin_amdgcn_s_setprio(0);
    __builtin_amdgcn_s_barrier();
  };
  auto VM0 = [&]() { asm volatile("s_waitcnt vmcnt(0)" ::: "memory"); };
  auto VML = [&]() {
    if constexpr (BN == 256) asm volatile("s_waitcnt vmcnt(3)" ::: "memory");
    else                     asm volatile("s_waitcnt vmcnt(2)" ::: "memory");
  };
  auto VM2L = [&]() {
    if constexpr (BN == 256) asm volatile("s_waitcnt vmcnt(6)" ::: "memory");
    else                     asm volatile("s_waitcnt vmcnt(4)" ::: "memory");
  };

  const int NT = K >> 5;

  STAGE(0, 0);
  STAGE(1, 1);
  VML();
  __builtin_amdgcn_s_barrier();

  int q0 = 0;
  for (int kt = 0; kt < NT - 2; ++kt) {
    int q2 = q0 + 2; if (q2 >= 3) q2 -= 3;
    STAGE(kt + 2, q2);
    VM2L();
    __builtin_amdgcn_s_barrier();
    COMPUTE(q0);
    q0 = (q0 == 2) ? 0 : q0 + 1;
  }
  VML();
  __builtin_amdgcn_s_barrier();
  COMPUTE(q0);
  q0 = (q0 == 2) ? 0 : q0 + 1;
  VM0();
  __builtin_amdgcn_s_barrier();
  COMPUTE(q0);

  const int orow = (l >> 4) << 2;
#pragma unroll
  for (int n = 0; n < NREP; n++) {
    size_t col = bcol + (size_t)wc * WN + n * 16 + lr;
    float bv = bias[col];
#pragma unroll
    for (int m = 0; m < 4; m++) {
      size_t row = brow + (size_t)wr * 64 + m * 16 + orow;
#pragma unroll
      for (int r = 0; r < 4; r++)
        Cout[(row + r) * (size_t)N + col] = acc[m][n][r] + bv;
    }
  }
}

// ---- L1 GEMM: BM=128 x BN=64, grid 512 blocks = 2/CU -----------------------
// Per-wave 64x16, acc[4][1]. LDS buf = A 8KB + B 4KB = 12KB; x3 = 36KB.
// B staged via 256-thread map duplicated across wave-halves (benign same-
// byte race); every wave issues exactly 2 GLD16/tile -> uniform vmcnt L=2.
__global__ __launch_bounds__(512, 4) void gemm64n(
    const __hip_bfloat16* __restrict__ A, const __hip_bfloat16* __restrict__ Bw,
    const float* __restrict__ bias, float* __restrict__ Cout, int N, int K) {
  constexpr int BUFB = 8192 + 4096;
  __shared__ __attribute__((aligned(16))) char lds[3 * BUFB];

  const int t = threadIdx.x;
  const int w = t >> 6, l = t & 63;
  const int wr = w >> 2, wc = w & 3;
  const int lr = l & 15;
  const int kbs = ((l >> 4) * 16) ^ (((lr >> 1) & 3) << 4);

  unsigned nwg = gridDim.x * gridDim.y;
  unsigned lin = blockIdx.y * gridDim.x + blockIdx.x;
  unsigned swz = (lin & 7) * (nwg >> 3) + (lin >> 3);
  unsigned bx = swz % gridDim.x, by = swz / gridDim.x;
  size_t brow = (size_t)by * 128, bcol = (size_t)bx * 64;

  f32x4 acc[4];
#pragma unroll
  for (int m = 0; m < 4; m++) acc[m] = (f32x4){0.f, 0.f, 0.f, 0.f};

  // A staging: thread t -> row t>>2 (0..127), 16B slot t&3 (swizzled)
  const int srow  = t >> 2;
  const int scolb = ((t & 3) * 16) ^ (((srow >> 1) & 3) << 4);
  const __hip_bfloat16* gA0 = A + (brow + srow) * (size_t)K + (scolb >> 1);
  // B staging: 256-thread map (t&255) -> row tb>>2 (0..63), slot tb&3
  const int tb  = t & 255;
  const int srB = tb >> 2;
  const int scB = ((tb & 3) * 16) ^ (((srB >> 1) & 3) << 4);
  const __hip_bfloat16* gB0 = Bw + (bcol + srB) * (size_t)K + (scB >> 1);

  char* ldsp = (char*)lds;
  const int paOff = (wr * 64 + lr) * 64 + kbs;
  const int pbOff = 8192 + (wc * 16 + lr) * 64 + kbs;

  auto STAGE = [&](int kt, int q) {
    char* bp = ldsp + q * BUFB;
    GLD16(gA0 + (kt << 5), bp + w * 1024);
    GLD16(gB0 + (kt << 5), bp + 8192 + (w & 3) * 1024);  // dup across halves
  };
  auto COMPUTE = [&](int q) {
    const char* pa = ldsp + q * BUFB + paOff;
    const char* pb = ldsp + q * BUFB + pbOff;
    short8 bq = *(const short8*)pb;
    short8 aq[4];
#pragma unroll
    for (int m = 0; m < 4; m++) aq[m] = *(const short8*)(pa + m * 1024);
    __builtin_amdgcn_s_setprio(1);
#pragma unroll
    for (int m = 0; m < 4; m++)
      acc[m] = __builtin_amdgcn_mfma_f32_16x16x32_bf16(aq[m], bq, acc[m], 0, 0, 0);
    __builtin_amdgcn_s_setprio(0);
    __builtin_amdgcn_s_barrier();
  };

  const int NT = K >> 5;   // 576

  STAGE(0, 0);
  STAGE(1, 1);
  asm volatile("s_waitcnt vmcnt(2)" ::: "memory");   // tile 0 landed
  __builtin_amdgcn_s_barrier();

  int q0 = 0;
  for (int kt = 0; kt < NT - 2; ++kt) {
    int q2 = q0 + 2; if (q2 >= 3) q2 -= 3;
    STAGE(kt + 2, q2);
    asm volatile("s_waitcnt vmcnt(4)" ::: "memory"); // tile kt landed
    __builtin_amdgcn_s_barrier();
    COMPUTE(q0);
    q0 = (q0 == 2) ? 0 : q0 + 1;
  }
  asm volatile("s_waitcnt vmcnt(2)" ::: "memory");   // tile NT-2 landed
  __builtin_amdgcn_s_barrier();
  COMPUTE(q0);
  q0 = (q0 == 2) ? 0 : q0 + 1;
  asm volatile("s_waitcnt vmcnt(0)" ::: "memory");   // tile NT-1 landed
  __builtin_amdgcn_s_barrier();
  COMPUTE(q0);

  const int orow = (l >> 4) << 2;
  size_t col = bcol + (size_t)wc * 16 + lr;
  float bv = bias[col];
#pragma unroll
  for (int m = 0; m < 4; m++) {
    size_t row = brow + (size_t)wr * 64 + m * 16 + orow;
#pragma unroll
    for (int r = 0; r < 4; r++)
      Cout[(row + r) * (size_t)N + col] = acc[m][r] + bv;
  }
}

// ---------------------------------------------------------------------------
extern "C" void kernel_launch(void* const* d_in, const int* in_sizes, int n_in,
                              void* d_out, int out_size, void* d_ws, size_t ws_size,
                              hipStream_t stream) {
  const float* x     = (const float*)d_in[0];
  const float* coef0 = (const float*)d_in[1];
  const float* sb0   = (const float*)d_in[2];
  const float* sp0   = (const float*)d_in[3];
  const float* mask0 = (const float*)d_in[4];
  const float* bias0 = (const float*)d_in[5];
  const float* coef1 = (const float*)d_in[6];
  const float* sb1   = (const float*)d_in[7];
  const float* sp1   = (const float*)d_in[8];
  const float* mask1 = (const float*)d_in[9];
  const float* bias1 = (const float*)d_in[10];
  float* out = (float*)d_out;

  const int B = 8192, D0 = 1024, D1 = 2048, D2 = 1024;
  const int K0 = 9 * D0;   // 9216
  const int K1 = 9 * D1;   // 18432
  const int CH = 4096;     // L1 batch chunk

  // ws (255,852,544 B total — r3-PROVEN):
  //   h1  [0, 67108864) | W [67108864, 104857600) | Aug [104857600, +151MB)
  char* ws = (char*)d_ws;
  float*          h1  = (float*)ws;
  __hip_bfloat16* W   = (__hip_bfloat16*)(ws + (size_t)67108864);
  __hip_bfloat16* Aug = (__hip_bfloat16*)(ws + (size_t)104857600);

  const long nW0 = (long)D1 * (D0 / 4);   // 524288
  const long nX0 = (long)B * (D0 / 8);    // 1048576
  const long nW1 = (long)D2 * (D1 / 4);   // 524288
  const long nX1 = (long)CH * (D1 / 8);   // 1048576

  // ---- layer 0: merged prep (W0 + Aug0), GEMM at 2 blocks/CU ----
  prep_merge<<<(unsigned)((nW0 + nX0) / 256), 256, 0, stream>>>(
      coef0, sb0, sp0, mask0, W, D0, nW0, x, Aug, D0, nX0);
  {
    dim3 g0(D1 / 256, B / 128);   // (8, 64) = 512 blocks
    gemm128<256><<<g0, 512, 0, stream>>>(Aug, W, bias0, h1, D1, K0);
  }

  // ---- layer 1: merged prep (W1 + Aug1 ch0), GEMM, expand ch1, GEMM ----
  prep_merge<<<(unsigned)((nW1 + nX1) / 256), 256, 0, stream>>>(
      coef1, sb1, sp1, mask1, W, D1, nW1, h1, Aug, D1, nX1);
  {
    dim3 g1(D2 / 64, CH / 128);   // (16, 32) = 512 blocks, 2/CU
    gemm64n<<<g1, 512, 0, stream>>>(Aug, W, bias1, out, D2, K1);
  }
  expand_aug<<<(unsigned)(nX1 / 256), 256, 0, stream>>>(
      h1 + (size_t)CH * D1, Aug, nX1, D1);
  {
    dim3 g1(D2 / 64, CH / 128);
    gemm64n<<<g1, 512, 0, stream>>>(Aug, W, bias1,
                                    out + (size_t)CH * D2, D2, K1);
  }
}

// Round 20
// 802.665 us; speedup vs baseline: 1.1910x; 1.1910x over previous
//
#include <hip/hip_runtime.h>
#include <hip/hip_bf16.h>
#include <cstdint>

// ---------------------------------------------------------------------------
// KAN 2-layer forward as two bf16 MFMA GEMMs (fp32 output).
// Round-20 = r18 (best, 790us; r19's BN=64 intensity-loss reverted) +
// L1 SPLIT-K (the occupancy fix that keeps the 128x128 tile):
//  * gemm128s: K=18432 split in 2 halves of 9216; grid (8,64)=512 blocks =
//    2 blocks/CU (was 256 = 1/CU). kz = swizzled-by>>5; z=0 -> out(+bias),
//    z=1 -> fp32 partial in the DEAD half of h1 (that chunk's rows were
//    already consumed by its expand). reduce_add folds partial (+8us).
//    Deterministic (no atomics). Same tile/schedule/swizzles as r18's L1.
//  * L0 path, prep_merge aux, ws layout: r18-FROZEN.
// ws = r3-proven 255,852,544 B: h1 | W | Aug region. CH=4096.
//   P0 = h1 bytes [0,16.8MB) (rows 0-4095 dead after ch0 expand);
//   P1 = h1 bytes [33.5MB,50.3MB) (rows 4096+ dead after ch1 expand).
// ---------------------------------------------------------------------------

typedef __attribute__((ext_vector_type(8))) short short8;
typedef __attribute__((ext_vector_type(4))) short short4v;
typedef __attribute__((ext_vector_type(4))) float f32x4;

#define GLD16(gp, lp)                                                          \
  __builtin_amdgcn_global_load_lds(                                           \
      (const __attribute__((address_space(1))) unsigned int*)(gp),             \
      (__attribute__((address_space(3))) unsigned int*)(lp), 16, 0, 0)

__device__ __forceinline__ unsigned short f2bf(float f) {
  __hip_bfloat16 h = __float2bfloat16(f);
  return *reinterpret_cast<unsigned short*>(&h);
}

__device__ __forceinline__ void basis8(float x, float* w, int& j) {
  float u  = (x + 2.2f) * 2.5f;
  float fj = floorf(u);
  j = (int)fj;
  float t  = u - fj;
  float omt = 1.0f - t;
  float t2 = t * t, t3 = t2 * t;
  w[0] = omt * omt * omt * (1.0f / 6.0f);                              // d==3
  w[1] = (3.0f * t3 - 6.0f * t2 + 4.0f) * (1.0f / 6.0f);               // d==2
  w[2] = (-3.0f * t3 + 3.0f * t2 + 3.0f * t + 1.0f) * (1.0f / 6.0f);   // d==1
  w[3] = t3 * (1.0f / 6.0f);                                           // d==0
}

// ---- prep_w item: W[o, kperm(c,i)], kperm = (i/64)*576 + c*64 + (i%64) ----
__device__ __forceinline__ void prep_w_item(
    long idx, const float* __restrict__ coef, const float* __restrict__ sb,
    const float* __restrict__ sp, const float* __restrict__ mask,
    __hip_bfloat16* __restrict__ W, int I) {
  int qtr = I >> 2;
  int iq = (int)(idx % qtr);
  int o  = (int)(idx / qtr);
  int i  = iq << 2;
  size_t oi = (size_t)o * I + i;
  float4 mk4 = *(const float4*)(mask + oi);
  float4 sp4 = *(const float4*)(sp + oi);
  float4 sb4 = *(const float4*)(sb + oi);
  float spm[4] = {sp4.x * mk4.x, sp4.y * mk4.y, sp4.z * mk4.z, sp4.w * mk4.w};
  float cf[4][8];
  const float4* cp = (const float4*)(coef + oi * 8);
#pragma unroll
  for (int e = 0; e < 4; e++) {
    float4 a = cp[e * 2], b = cp[e * 2 + 1];
    cf[e][0] = a.x; cf[e][1] = a.y; cf[e][2] = a.z; cf[e][3] = a.w;
    cf[e][4] = b.x; cf[e][5] = b.y; cf[e][6] = b.z; cf[e][7] = b.w;
  }
  __hip_bfloat16* base = W + (size_t)o * (size_t)(9 * I) + (i >> 6) * 576 + (i & 63);
#pragma unroll
  for (int c = 0; c < 8; c++) {
    short4v pk;
#pragma unroll
    for (int e = 0; e < 4; e++) pk[e] = (short)f2bf(cf[e][c] * spm[e]);
    *(short4v*)(base + c * 64) = pk;
  }
  short4v ps;
  ps[0] = (short)f2bf(sb4.x * mk4.x); ps[1] = (short)f2bf(sb4.y * mk4.y);
  ps[2] = (short)f2bf(sb4.z * mk4.z); ps[3] = (short)f2bf(sb4.w * mk4.w);
  *(short4v*)(base + 8 * 64) = ps;
}

// ---- expand item: Aug[b, kperm(c,i)], 8 elems ------------------------------
__device__ __forceinline__ void expand_item(
    long idx, const float* __restrict__ src, __hip_bfloat16* __restrict__ aug,
    int I) {
  int  oct = I >> 3;
  int  io = (int)(idx % oct);
  long b  = idx / oct;
  int  i  = io << 3;
  const float* sp = src + b * (size_t)I + i;
  float4 xa = *(const float4*)sp;
  float4 xb = *(const float4*)(sp + 4);
  float xv[8] = {xa.x, xa.y, xa.z, xa.w, xb.x, xb.y, xb.z, xb.w};

  float w[8][4], s[8];
  int   j[8];
#pragma unroll
  for (int e = 0; e < 8; e++) {
    float xe = xv[e];
    s[e] = xe / (1.0f + __expf(-xe));
    basis8(xe, w[e], j[e]);
  }
  __hip_bfloat16* base = aug + b * (size_t)(9 * I) + (i >> 6) * 576 + (i & 63);
#pragma unroll
  for (int c = 0; c < 8; c++) {
    short8 pk;
#pragma unroll
    for (int e = 0; e < 8; e++) {
      int d = j[e] - c;
      float v = 0.0f;
      v = (d == 0) ? w[e][3] : v;
      v = (d == 1) ? w[e][2] : v;
      v = (d == 2) ? w[e][1] : v;
      v = (d == 3) ? w[e][0] : v;
      pk[e] = (short)f2bf(v);
    }
    *(short8*)(base + c * 64) = pk;
  }
  short8 ps;
#pragma unroll
  for (int e = 0; e < 8; e++) ps[e] = (short)f2bf(s[e]);
  *(short8*)(base + 8 * 64) = ps;
}

// ---- merged prep: {W-pack items} then {expand octets} ----------------------
__global__ void prep_merge(
    const float* __restrict__ coef, const float* __restrict__ sb,
    const float* __restrict__ sp, const float* __restrict__ mask,
    __hip_bfloat16* __restrict__ W, int IW, long nW,
    const float* __restrict__ xsrc, __hip_bfloat16* __restrict__ aug,
    int IX, long nX) {
  long idx = (long)blockIdx.x * blockDim.x + threadIdx.x;
  if (idx < nW)            prep_w_item(idx, coef, sb, sp, mask, W, IW);
  else if (idx < nW + nX)  expand_item(idx - nW, xsrc, aug, IX);
}

__global__ void expand_aug(const float* __restrict__ src,
                           __hip_bfloat16* __restrict__ aug,
                           long totalOcts, int I) {
  long idx = (long)blockIdx.x * blockDim.x + threadIdx.x;
  if (idx >= totalOcts) return;
  expand_item(idx, src, aug, I);
}

// ---- reduce: out[i] += part[i], float4 -------------------------------------
__global__ void reduce_add(float* __restrict__ out, const float* __restrict__ part,
                           long n4) {
  long i = (long)blockIdx.x * blockDim.x + threadIdx.x;
  if (i >= n4) return;
  float4 a = *(const float4*)(out + i * 4);
  float4 b = *(const float4*)(part + i * 4);
  a.x += b.x; a.y += b.y; a.z += b.z; a.w += b.w;
  *(float4*)(out + i * 4) = a;
}

// ---- L0 GEMM (r15-verbatim): BM=128 x BN, 3-buf depth-2, counted vmcnt -----
template <int BN>
__global__ __launch_bounds__(512, 4) void gemm128(
    const __hip_bfloat16* __restrict__ A, const __hip_bfloat16* __restrict__ Bw,
    const float* __restrict__ bias, float* __restrict__ Cout, int N, int K) {
  constexpr int WN   = BN / 4;
  constexpr int NREP = BN / 64;
  constexpr int BUFB = 8192 + BN * 64;
  __shared__ __attribute__((aligned(16))) char lds[3 * BUFB];

  const int t = threadIdx.x;
  const int w = t >> 6, l = t & 63;
  const int wr = w >> 2, wc = w & 3;
  const int lr = l & 15;
  const int kbs = ((l >> 4) * 16) ^ (((lr >> 1) & 3) << 4);

  unsigned nwg = gridDim.x * gridDim.y;
  unsigned lin = blockIdx.y * gridDim.x + blockIdx.x;
  unsigned swz = (lin & 7) * (nwg >> 3) + (lin >> 3);
  unsigned bx = swz % gridDim.x, by = swz / gridDim.x;
  size_t brow = (size_t)by * 128, bcol = (size_t)bx * BN;

  f32x4 acc[4][NREP];
#pragma unroll
  for (int m = 0; m < 4; m++)
#pragma unroll
    for (int n = 0; n < NREP; n++) acc[m][n] = (f32x4){0.f, 0.f, 0.f, 0.f};

  const int srow  = t >> 2;
  const int scolb = ((t & 3) * 16) ^ (((srow >> 1) & 3) << 4);
  const __hip_bfloat16* gA0 = A + (brow + srow) * (size_t)K + (scolb >> 1);
  const __hip_bfloat16* gB0 = Bw + (bcol + srow) * (size_t)K + (scolb >> 1);
  const __hip_bfloat16* gB1 = gB0 + (size_t)128 * K;

  char* ldsp = (char*)lds;
  const int paOff = (wr * 64 + lr) * 64 + kbs;
  const int pbOff = 8192 + (wc * WN + lr) * 64 + kbs;

  auto STAGE = [&](int kt, int q) {
    char* bp = ldsp + q * BUFB;
    GLD16(gA0 + (kt << 5), bp + w * 1024);
    GLD16(gB0 + (kt << 5), bp + 8192 + w * 1024);
    if constexpr (BN == 256) GLD16(gB1 + (kt << 5), bp + 16384 + w * 1024);
  };
  auto COMPUTE = [&](int q) {
    const char* pa = ldsp + q * BUFB + paOff;
    const char* pb = ldsp + q * BUFB + pbOff;
    short8 bq[NREP], aq[4];
#pragma unroll
    for (int n = 0; n < NREP; n++) bq[n] = *(const short8*)(pb + n * 1024);
#pragma unroll
    for (int m = 0; m < 4; m++) aq[m] = *(const short8*)(pa + m * 1024);
    __builtin_amdgcn_s_setprio(1);
#pragma unroll
    for (int m = 0; m < 4; m++)
#pragma unroll
      for (int n = 0; n < NREP; n++)
        acc[m][n] = __builtin_amdgcn_mfma_f32_16x16x32_bf16(aq[m], bq[n], acc[m][n], 0, 0, 0);
    __builtin_amdgcn_s_setprio(0);
    __builtin_amdgcn_s_barrier();
  };
  auto VM0 = [&]() { asm volatile("s_waitcnt vmcnt(0)" ::: "memory"); };
  auto VML = [&]() {
    if constexpr (BN == 256) asm volatile("s_waitcnt vmcnt(3)" ::: "memory");
    else                     asm volatile("s_waitcnt vmcnt(2)" ::: "memory");
  };
  auto VM2L = [&]() {
    if constexpr (BN == 256) asm volatile("s_waitcnt vmcnt(6)" ::: "memory");
    else                     asm volatile("s_waitcnt vmcnt(4)" ::: "memory");
  };

  const int NT = K >> 5;

  STAGE(0, 0);
  STAGE(1, 1);
  VML();
  __builtin_amdgcn_s_barrier();

  int q0 = 0;
  for (int kt = 0; kt < NT - 2; ++kt) {
    int q2 = q0 + 2; if (q2 >= 3) q2 -= 3;
    STAGE(kt + 2, q2);
    VM2L();
    __builtin_amdgcn_s_barrier();
    COMPUTE(q0);
    q0 = (q0 == 2) ? 0 : q0 + 1;
  }
  VML();
  __builtin_amdgcn_s_barrier();
  COMPUTE(q0);
  q0 = (q0 == 2) ? 0 : q0 + 1;
  VM0();
  __builtin_amdgcn_s_barrier();
  COMPUTE(q0);

  const int orow = (l >> 4) << 2;
#pragma unroll
  for (int n = 0; n < NREP; n++) {
    size_t col = bcol + (size_t)wc * WN + n * 16 + lr;
    float bv = bias[col];
#pragma unroll
    for (int m = 0; m < 4; m++) {
      size_t row = brow + (size_t)wr * 64 + m * 16 + orow;
#pragma unroll
      for (int r = 0; r < 4; r++)
        Cout[(row + r) * (size_t)N + col] = acc[m][n][r] + bv;
    }
  }
}

// ---- L1 split-K GEMM: BM=128 x BN=128, K halves, 512 blocks = 2/CU ---------
// grid (8,64): swizzled by in 0..63 -> kz = by>>5 (K-half), brow = (by&31)*128.
// z=0 writes out(+bias); z=1 writes fp32 partial (no bias). Same schedule/
// swizzles as gemm128<128>; K is the row stride, KS=9216 the per-split depth.
__global__ __launch_bounds__(512, 4) void gemm128s(
    const __hip_bfloat16* __restrict__ A, const __hip_bfloat16* __restrict__ Bw,
    const float* __restrict__ bias, float* __restrict__ Cout,
    float* __restrict__ Part, int N, int K, int KS) {
  constexpr int BUFB = 8192 + 8192;
  __shared__ __attribute__((aligned(16))) char lds[3 * BUFB];

  const int t = threadIdx.x;
  const int w = t >> 6, l = t & 63;
  const int wr = w >> 2, wc = w & 3;
  const int lr = l & 15;
  const int kbs = ((l >> 4) * 16) ^ (((lr >> 1) & 3) << 4);

  unsigned nwg = gridDim.x * gridDim.y;
  unsigned lin = blockIdx.y * gridDim.x + blockIdx.x;
  unsigned swz = (lin & 7) * (nwg >> 3) + (lin >> 3);
  unsigned bx = swz % gridDim.x, byf = swz / gridDim.x;
  const int kz = (int)(byf >> 5);          // K-half
  size_t brow = (size_t)(byf & 31) * 128, bcol = (size_t)bx * 128;
  const int kofs = kz * KS;

  f32x4 acc[4][2];
#pragma unroll
  for (int m = 0; m < 4; m++)
#pragma unroll
    for (int n = 0; n < 2; n++) acc[m][n] = (f32x4){0.f, 0.f, 0.f, 0.f};

  const int srow  = t >> 2;
  const int scolb = ((t & 3) * 16) ^ (((srow >> 1) & 3) << 4);
  const __hip_bfloat16* gA0 = A + (brow + srow) * (size_t)K + kofs + (scolb >> 1);
  const __hip_bfloat16* gB0 = Bw + (bcol + srow) * (size_t)K + kofs + (scolb >> 1);

  char* ldsp = (char*)lds;
  const int paOff = (wr * 64 + lr) * 64 + kbs;
  const int pbOff = 8192 + (wc * 32 + lr) * 64 + kbs;

  auto STAGE = [&](int kt, int q) {
    char* bp = ldsp + q * BUFB;
    GLD16(gA0 + (kt << 5), bp + w * 1024);
    GLD16(gB0 + (kt << 5), bp + 8192 + w * 1024);
  };
  auto COMPUTE = [&](int q) {
    const char* pa = ldsp + q * BUFB + paOff;
    const char* pb = ldsp + q * BUFB + pbOff;
    short8 bq[2], aq[4];
#pragma unroll
    for (int n = 0; n < 2; n++) bq[n] = *(const short8*)(pb + n * 1024);
#pragma unroll
    for (int m = 0; m < 4; m++) aq[m] = *(const short8*)(pa + m * 1024);
    __builtin_amdgcn_s_setprio(1);
#pragma unroll
    for (int m = 0; m < 4; m++)
#pragma unroll
      for (int n = 0; n < 2; n++)
        acc[m][n] = __builtin_amdgcn_mfma_f32_16x16x32_bf16(aq[m], bq[n], acc[m][n], 0, 0, 0);
    __builtin_amdgcn_s_setprio(0);
    __builtin_amdgcn_s_barrier();
  };

  const int NT = KS >> 5;   // 288

  STAGE(0, 0);
  STAGE(1, 1);
  asm volatile("s_waitcnt vmcnt(2)" ::: "memory");
  __builtin_amdgcn_s_barrier();

  int q0 = 0;
  for (int kt = 0; kt < NT - 2; ++kt) {
    int q2 = q0 + 2; if (q2 >= 3) q2 -= 3;
    STAGE(kt + 2, q2);
    asm volatile("s_waitcnt vmcnt(4)" ::: "memory");
    __builtin_amdgcn_s_barrier();
    COMPUTE(q0);
    q0 = (q0 == 2) ? 0 : q0 + 1;
  }
  asm volatile("s_waitcnt vmcnt(2)" ::: "memory");
  __builtin_amdgcn_s_barrier();
  COMPUTE(q0);
  q0 = (q0 == 2) ? 0 : q0 + 1;
  asm volatile("s_waitcnt vmcnt(0)" ::: "memory");
  __builtin_amdgcn_s_barrier();
  COMPUTE(q0);

  const int orow = (l >> 4) << 2;
  float* C = (kz == 0) ? Cout : Part;
#pragma unroll
  for (int n = 0; n < 2; n++) {
    size_t col = bcol + (size_t)wc * 32 + n * 16 + lr;
    float bv = (kz == 0) ? bias[col] : 0.0f;
#pragma unroll
    for (int m = 0; m < 4; m++) {
      size_t row = brow + (size_t)wr * 64 + m * 16 + orow;
#pragma unroll
      for (int r = 0; r < 4; r++)
        C[(row + r) * (size_t)N + col] = acc[m][n][r] + bv;
    }
  }
}

// ---------------------------------------------------------------------------
extern "C" void kernel_launch(void* const* d_in, const int* in_sizes, int n_in,
                              void* d_out, int out_size, void* d_ws, size_t ws_size,
                              hipStream_t stream) {
  const float* x     = (const float*)d_in[0];
  const float* coef0 = (const float*)d_in[1];
  const float* sb0   = (const float*)d_in[2];
  const float* sp0   = (const float*)d_in[3];
  const float* mask0 = (const float*)d_in[4];
  const float* bias0 = (const float*)d_in[5];
  const float* coef1 = (const float*)d_in[6];
  const float* sb1   = (const float*)d_in[7];
  const float* sp1   = (const float*)d_in[8];
  const float* mask1 = (const float*)d_in[9];
  const float* bias1 = (const float*)d_in[10];
  float* out = (float*)d_out;

  const int B = 8192, D0 = 1024, D1 = 2048, D2 = 1024;
  const int K0 = 9 * D0;   // 9216
  const int K1 = 9 * D1;   // 18432
  const int CH = 4096;     // L1 batch chunk

  // ws (255,852,544 B — r3-PROVEN):
  //   h1 [0,67108864) | W [67108864,104857600) | Aug [104857600,+151MB)
  //   P0 = h1 rows [0,4096) region (dead after ch0 expand);
  //   P1 = h1 rows [4096,8192) region (dead after ch1 expand).
  char* ws = (char*)d_ws;
  float*          h1  = (float*)ws;
  __hip_bfloat16* W   = (__hip_bfloat16*)(ws + (size_t)67108864);
  __hip_bfloat16* Aug = (__hip_bfloat16*)(ws + (size_t)104857600);
  float* P0 = (float*)ws;
  float* P1 = (float*)(ws + (size_t)33554432);

  const long nW0 = (long)D1 * (D0 / 4);   // 524288
  const long nX0 = (long)B * (D0 / 8);    // 1048576
  const long nW1 = (long)D2 * (D1 / 4);   // 524288
  const long nX1 = (long)CH * (D1 / 8);   // 1048576
  const long n4  = (long)CH * D2 / 4;     // 1048576 float4s per chunk

  // ---- layer 0: merged prep (W0 + Aug0), GEMM at 2 blocks/CU ----
  prep_merge<<<(unsigned)((nW0 + nX0) / 256), 256, 0, stream>>>(
      coef0, sb0, sp0, mask0, W, D0, nW0, x, Aug, D0, nX0);
  {
    dim3 g0(D1 / 256, B / 128);   // (8, 64) = 512 blocks
    gemm128<256><<<g0, 512, 0, stream>>>(Aug, W, bias0, h1, D1, K0);
  }

  // ---- layer 1 ch0: merged prep (W1 + expand ch0), split-K GEMM, reduce ----
  prep_merge<<<(unsigned)((nW1 + nX1) / 256), 256, 0, stream>>>(
      coef1, sb1, sp1, mask1, W, D1, nW1, h1, Aug, D1, nX1);
  {
    dim3 g1(D2 / 128, 2 * CH / 128);   // (8, 64) = 512 blocks, 2/CU
    gemm128s<<<g1, 512, 0, stream>>>(Aug, W, bias1, out, P0, D2, K1, K1 / 2);
    reduce_add<<<(unsigned)(n4 / 256), 256, 0, stream>>>(out, P0, n4);
  }

  // ---- layer 1 ch1: expand, split-K GEMM, reduce ----
  expand_aug<<<(unsigned)(nX1 / 256), 256, 0, stream>>>(
      h1 + (size_t)CH * D1, Aug, nX1, D1);
  {
    dim3 g1(D2 / 128, 2 * CH / 128);
    gemm128s<<<g1, 512, 0, stream>>>(Aug, W, bias1, out + (size_t)CH * D2,
                                     P1, D2, K1, K1 / 2);
    reduce_add<<<(unsigned)(n4 / 256), 256, 0, stream>>>(out + (size_t)CH * D2, P1, n4);
  }
}

// Round 21
// 789.420 us; speedup vs baseline: 1.2109x; 1.0168x over previous
//
#include <hip/hip_runtime.h>
#include <hip/hip_bf16.h>
#include <cstdint>

// ---------------------------------------------------------------------------
// KAN 2-layer forward as two bf16 MFMA GEMMs (fp32 output).
// Round-21 = r18 (best, 790us; r19 BN=64 and r20 split-K both reverted as
// regressions/neutral) + NON-TEMPORAL C-STORES:
//  * Diagnosis: L0/L1 GEMMs fetch 655-660MB from HBM vs a 189MB footprint
//    (3.5x refetch; FETCH/2.3TB/s ~= dur -> HBM-refetch-bound, which is why
//    4 schedule variants were all null). Cause hypothesis: C-write streams
//    (h1 67MB / out) write-allocate into L3 while A/B stream -> footprint +
//    write stream ~= 256MB L3 -> continuous eviction of A/B.
//  * Fix: __builtin_nontemporal_store for GEMM C-writes only (h1, out —
//    written once, read much later/never). Aug/W writes stay cached (read
//    immediately by the GEMMs).
//  * Everything else r18-VERBATIM: gemm128 BM=128 3-buf depth-2 counted
//    vmcnt, 0-conflict swizzle both-sides, XCD swizzle, setprio, (512,4)
//    2 blocks/CU; prep_merge aux; r3-proven 255.8MB ws; CH=4096.
// ---------------------------------------------------------------------------

typedef __attribute__((ext_vector_type(8))) short short8;
typedef __attribute__((ext_vector_type(4))) short short4v;
typedef __attribute__((ext_vector_type(4))) float f32x4;

#define GLD16(gp, lp)                                                          \
  __builtin_amdgcn_global_load_lds(                                           \
      (const __attribute__((address_space(1))) unsigned int*)(gp),             \
      (__attribute__((address_space(3))) unsigned int*)(lp), 16, 0, 0)

__device__ __forceinline__ unsigned short f2bf(float f) {
  __hip_bfloat16 h = __float2bfloat16(f);
  return *reinterpret_cast<unsigned short*>(&h);
}

__device__ __forceinline__ void basis8(float x, float* w, int& j) {
  float u  = (x + 2.2f) * 2.5f;
  float fj = floorf(u);
  j = (int)fj;
  float t  = u - fj;
  float omt = 1.0f - t;
  float t2 = t * t, t3 = t2 * t;
  w[0] = omt * omt * omt * (1.0f / 6.0f);                              // d==3
  w[1] = (3.0f * t3 - 6.0f * t2 + 4.0f) * (1.0f / 6.0f);               // d==2
  w[2] = (-3.0f * t3 + 3.0f * t2 + 3.0f * t + 1.0f) * (1.0f / 6.0f);   // d==1
  w[3] = t3 * (1.0f / 6.0f);                                           // d==0
}

// ---- prep_w item: W[o, kperm(c,i)], kperm = (i/64)*576 + c*64 + (i%64) ----
__device__ __forceinline__ void prep_w_item(
    long idx, const float* __restrict__ coef, const float* __restrict__ sb,
    const float* __restrict__ sp, const float* __restrict__ mask,
    __hip_bfloat16* __restrict__ W, int I) {
  int qtr = I >> 2;
  int iq = (int)(idx % qtr);
  int o  = (int)(idx / qtr);
  int i  = iq << 2;
  size_t oi = (size_t)o * I + i;
  float4 mk4 = *(const float4*)(mask + oi);
  float4 sp4 = *(const float4*)(sp + oi);
  float4 sb4 = *(const float4*)(sb + oi);
  float spm[4] = {sp4.x * mk4.x, sp4.y * mk4.y, sp4.z * mk4.z, sp4.w * mk4.w};
  float cf[4][8];
  const float4* cp = (const float4*)(coef + oi * 8);
#pragma unroll
  for (int e = 0; e < 4; e++) {
    float4 a = cp[e * 2], b = cp[e * 2 + 1];
    cf[e][0] = a.x; cf[e][1] = a.y; cf[e][2] = a.z; cf[e][3] = a.w;
    cf[e][4] = b.x; cf[e][5] = b.y; cf[e][6] = b.z; cf[e][7] = b.w;
  }
  __hip_bfloat16* base = W + (size_t)o * (size_t)(9 * I) + (i >> 6) * 576 + (i & 63);
#pragma unroll
  for (int c = 0; c < 8; c++) {
    short4v pk;
#pragma unroll
    for (int e = 0; e < 4; e++) pk[e] = (short)f2bf(cf[e][c] * spm[e]);
    *(short4v*)(base + c * 64) = pk;
  }
  short4v ps;
  ps[0] = (short)f2bf(sb4.x * mk4.x); ps[1] = (short)f2bf(sb4.y * mk4.y);
  ps[2] = (short)f2bf(sb4.z * mk4.z); ps[3] = (short)f2bf(sb4.w * mk4.w);
  *(short4v*)(base + 8 * 64) = ps;
}

// ---- expand item: Aug[b, kperm(c,i)], 8 elems ------------------------------
__device__ __forceinline__ void expand_item(
    long idx, const float* __restrict__ src, __hip_bfloat16* __restrict__ aug,
    int I) {
  int  oct = I >> 3;
  int  io = (int)(idx % oct);
  long b  = idx / oct;
  int  i  = io << 3;
  const float* sp = src + b * (size_t)I + i;
  float4 xa = *(const float4*)sp;
  float4 xb = *(const float4*)(sp + 4);
  float xv[8] = {xa.x, xa.y, xa.z, xa.w, xb.x, xb.y, xb.z, xb.w};

  float w[8][4], s[8];
  int   j[8];
#pragma unroll
  for (int e = 0; e < 8; e++) {
    float xe = xv[e];
    s[e] = xe / (1.0f + __expf(-xe));
    basis8(xe, w[e], j[e]);
  }
  __hip_bfloat16* base = aug + b * (size_t)(9 * I) + (i >> 6) * 576 + (i & 63);
#pragma unroll
  for (int c = 0; c < 8; c++) {
    short8 pk;
#pragma unroll
    for (int e = 0; e < 8; e++) {
      int d = j[e] - c;
      float v = 0.0f;
      v = (d == 0) ? w[e][3] : v;
      v = (d == 1) ? w[e][2] : v;
      v = (d == 2) ? w[e][1] : v;
      v = (d == 3) ? w[e][0] : v;
      pk[e] = (short)f2bf(v);
    }
    *(short8*)(base + c * 64) = pk;
  }
  short8 ps;
#pragma unroll
  for (int e = 0; e < 8; e++) ps[e] = (short)f2bf(s[e]);
  *(short8*)(base + 8 * 64) = ps;
}

// ---- merged prep: {W-pack items} then {expand octets} ----------------------
__global__ void prep_merge(
    const float* __restrict__ coef, const float* __restrict__ sb,
    const float* __restrict__ sp, const float* __restrict__ mask,
    __hip_bfloat16* __restrict__ W, int IW, long nW,
    const float* __restrict__ xsrc, __hip_bfloat16* __restrict__ aug,
    int IX, long nX) {
  long idx = (long)blockIdx.x * blockDim.x + threadIdx.x;
  if (idx < nW)            prep_w_item(idx, coef, sb, sp, mask, W, IW);
  else if (idx < nW + nX)  expand_item(idx - nW, xsrc, aug, IX);
}

__global__ void expand_aug(const float* __restrict__ src,
                           __hip_bfloat16* __restrict__ aug,
                           long totalOcts, int I) {
  long idx = (long)blockIdx.x * blockDim.x + threadIdx.x;
  if (idx >= totalOcts) return;
  expand_item(idx, src, aug, I);
}

// ---- 128xBN GEMM (r15/r18 schedule; nt C-store): C = A*Bw^T + bias ---------
// BM=128, BN 256/128, BK=32, 8 waves 2Mx4N, 3 buffers, depth-2 counted vmcnt.
// LDS 72/48KB -> 2 blocks/CU at (512,4). 0-conflict swizzle both-sides.
template <int BN>
__global__ __launch_bounds__(512, 4) void gemm128(
    const __hip_bfloat16* __restrict__ A, const __hip_bfloat16* __restrict__ Bw,
    const float* __restrict__ bias, float* __restrict__ Cout, int N, int K) {
  constexpr int WN   = BN / 4;
  constexpr int NREP = BN / 64;
  constexpr int BUFB = 8192 + BN * 64;
  __shared__ __attribute__((aligned(16))) char lds[3 * BUFB];

  const int t = threadIdx.x;
  const int w = t >> 6, l = t & 63;
  const int wr = w >> 2, wc = w & 3;
  const int lr = l & 15;
  const int kbs = ((l >> 4) * 16) ^ (((lr >> 1) & 3) << 4);

  unsigned nwg = gridDim.x * gridDim.y;
  unsigned lin = blockIdx.y * gridDim.x + blockIdx.x;
  unsigned swz = (lin & 7) * (nwg >> 3) + (lin >> 3);
  unsigned bx = swz % gridDim.x, by = swz / gridDim.x;
  size_t brow = (size_t)by * 128, bcol = (size_t)bx * BN;

  f32x4 acc[4][NREP];
#pragma unroll
  for (int m = 0; m < 4; m++)
#pragma unroll
    for (int n = 0; n < NREP; n++) acc[m][n] = (f32x4){0.f, 0.f, 0.f, 0.f};

  const int srow  = t >> 2;
  const int scolb = ((t & 3) * 16) ^ (((srow >> 1) & 3) << 4);
  const __hip_bfloat16* gA0 = A + (brow + srow) * (size_t)K + (scolb >> 1);
  const __hip_bfloat16* gB0 = Bw + (bcol + srow) * (size_t)K + (scolb >> 1);
  const __hip_bfloat16* gB1 = gB0 + (size_t)128 * K;

  char* ldsp = (char*)lds;
  const int paOff = (wr * 64 + lr) * 64 + kbs;
  const int pbOff = 8192 + (wc * WN + lr) * 64 + kbs;

  auto STAGE = [&](int kt, int q) {
    char* bp = ldsp + q * BUFB;
    GLD16(gA0 + (kt << 5), bp + w * 1024);
    GLD16(gB0 + (kt << 5), bp + 8192 + w * 1024);
    if constexpr (BN == 256) GLD16(gB1 + (kt << 5), bp + 16384 + w * 1024);
  };
  auto COMPUTE = [&](int q) {
    const char* pa = ldsp + q * BUFB + paOff;
    const char* pb = ldsp + q * BUFB + pbOff;
    short8 bq[NREP], aq[4];
#pragma unroll
    for (int n = 0; n < NREP; n++) bq[n] = *(const short8*)(pb + n * 1024);
#pragma unroll
    for (int m = 0; m < 4; m++) aq[m] = *(const short8*)(pa + m * 1024);
    __builtin_amdgcn_s_setprio(1);
#pragma unroll
    for (int m = 0; m < 4; m++)
#pragma unroll
      for (int n = 0; n < NREP; n++)
        acc[m][n] = __builtin_amdgcn_mfma_f32_16x16x32_bf16(aq[m], bq[n], acc[m][n], 0, 0, 0);
    __builtin_amdgcn_s_setprio(0);
    __builtin_amdgcn_s_barrier();
  };
  auto VM0 = [&]() { asm volatile("s_waitcnt vmcnt(0)" ::: "memory"); };
  auto VML = [&]() {
    if constexpr (BN == 256) asm volatile("s_waitcnt vmcnt(3)" ::: "memory");
    else                     asm volatile("s_waitcnt vmcnt(2)" ::: "memory");
  };
  auto VM2L = [&]() {
    if constexpr (BN == 256) asm volatile("s_waitcnt vmcnt(6)" ::: "memory");
    else                     asm volatile("s_waitcnt vmcnt(4)" ::: "memory");
  };

  const int NT = K >> 5;

  STAGE(0, 0);
  STAGE(1, 1);
  VML();
  __builtin_amdgcn_s_barrier();

  int q0 = 0;
  for (int kt = 0; kt < NT - 2; ++kt) {
    int q2 = q0 + 2; if (q2 >= 3) q2 -= 3;
    STAGE(kt + 2, q2);
    VM2L();
    __builtin_amdgcn_s_barrier();
    COMPUTE(q0);
    q0 = (q0 == 2) ? 0 : q0 + 1;
  }
  VML();
  __builtin_amdgcn_s_barrier();
  COMPUTE(q0);
  q0 = (q0 == 2) ? 0 : q0 + 1;
  VM0();
  __builtin_amdgcn_s_barrier();
  COMPUTE(q0);

  // epilogue: non-temporal C-stores (evict-first; C is never re-read soon)
  const int orow = (l >> 4) << 2;
#pragma unroll
  for (int n = 0; n < NREP; n++) {
    size_t col = bcol + (size_t)wc * WN + n * 16 + lr;
    float bv = bias[col];
#pragma unroll
    for (int m = 0; m < 4; m++) {
      size_t row = brow + (size_t)wr * 64 + m * 16 + orow;
#pragma unroll
      for (int r = 0; r < 4; r++)
        __builtin_nontemporal_store(acc[m][n][r] + bv,
                                    &Cout[(row + r) * (size_t)N + col]);
    }
  }
}

// ---------------------------------------------------------------------------
extern "C" void kernel_launch(void* const* d_in, const int* in_sizes, int n_in,
                              void* d_out, int out_size, void* d_ws, size_t ws_size,
                              hipStream_t stream) {
  const float* x     = (const float*)d_in[0];
  const float* coef0 = (const float*)d_in[1];
  const float* sb0   = (const float*)d_in[2];
  const float* sp0   = (const float*)d_in[3];
  const float* mask0 = (const float*)d_in[4];
  const float* bias0 = (const float*)d_in[5];
  const float* coef1 = (const float*)d_in[6];
  const float* sb1   = (const float*)d_in[7];
  const float* sp1   = (const float*)d_in[8];
  const float* mask1 = (const float*)d_in[9];
  const float* bias1 = (const float*)d_in[10];
  float* out = (float*)d_out;

  const int B = 8192, D0 = 1024, D1 = 2048, D2 = 1024;
  const int K0 = 9 * D0;   // 9216
  const int K1 = 9 * D1;   // 18432
  const int CH = 4096;     // L1 batch chunk

  // ws (255,852,544 B total — r3-PROVEN):
  //   h1  [0, 67108864) | W [67108864, 104857600) | Aug [104857600, +151MB)
  char* ws = (char*)d_ws;
  float*          h1  = (float*)ws;
  __hip_bfloat16* W   = (__hip_bfloat16*)(ws + (size_t)67108864);
  __hip_bfloat16* Aug = (__hip_bfloat16*)(ws + (size_t)104857600);

  const long nW0 = (long)D1 * (D0 / 4);   // 524288
  const long nX0 = (long)B * (D0 / 8);    // 1048576
  const long nW1 = (long)D2 * (D1 / 4);   // 524288
  const long nX1 = (long)CH * (D1 / 8);   // 1048576

  // ---- layer 0: merged prep (W0 + Aug0), GEMM at 2 blocks/CU ----
  prep_merge<<<(unsigned)((nW0 + nX0) / 256), 256, 0, stream>>>(
      coef0, sb0, sp0, mask0, W, D0, nW0, x, Aug, D0, nX0);
  {
    dim3 g0(D1 / 256, B / 128);   // (8, 64) = 512 blocks
    gemm128<256><<<g0, 512, 0, stream>>>(Aug, W, bias0, h1, D1, K0);
  }

  // ---- layer 1: merged prep (W1 + Aug1 ch0), GEMM, expand ch1, GEMM ----
  prep_merge<<<(unsigned)((nW1 + nX1) / 256), 256, 0, stream>>>(
      coef1, sb1, sp1, mask1, W, D1, nW1, h1, Aug, D1, nX1);
  {
    dim3 g1(D2 / 128, CH / 128);   // (8, 32) = 256 blocks
    gemm128<128><<<g1, 512, 0, stream>>>(Aug, W, bias1, out, D2, K1);
  }
  expand_aug<<<(unsigned)(nX1 / 256), 256, 0, stream>>>(
      h1 + (size_t)CH * D1, Aug, nX1, D1);
  {
    dim3 g1(D2 / 128, CH / 128);
    gemm128<128><<<g1, 512, 0, stream>>>(Aug, W, bias1,
                                         out + (size_t)CH * D2, D2, K1);
  }
}